// Round 4
// baseline (226.489 us; speedup 1.0000x reference)
//
#include <hip/hip_runtime.h>
#include <math.h>

#define BATCH   16384
#define IMGPIX  784           // 28*28
#define NTOT    (BATCH * IMGPIX)
#define NSLOT   64            // atomic spread slots per stage
#define SLOTSTR 8             // doubles per slot (64B stride); [0]=sum [1]=sumsq
#define STAGE_DBL (NSLOT * SLOTSTR)
#define LROWS   30            // row-padded LDS image: rows 0 and 29 are zeros

__device__ __forceinline__ void block_reduce_stats(float s, float q, double* slot) {
    #pragma unroll
    for (int off = 32; off >= 1; off >>= 1) {
        s += __shfl_down(s, off, 64);
        q += __shfl_down(q, off, 64);
    }
    __shared__ float red_s[4], red_q[4];
    int lane = threadIdx.x & 63;
    int wid  = threadIdx.x >> 6;
    if (lane == 0) { red_s[wid] = s; red_q[wid] = q; }
    __syncthreads();
    if (threadIdx.x == 0) {
        float ts = red_s[0] + red_s[1] + red_s[2] + red_s[3];
        float tq = red_q[0] + red_q[1] + red_q[2] + red_q[3];
        atomicAdd(&slot[0], (double)ts);
        atomicAdd(&slot[1], (double)tq);
    }
}

// Every wave redundantly reduces the 64 stat slots (2 doubles per lane) and
// broadcasts; returns (a, b) such that bn(x) = a*x + b. No barrier needed.
__device__ __forceinline__ float2 stats_ab(const double* __restrict__ stats_in,
                                           float gamma, float beta) {
    int lane = threadIdx.x & 63;
    double s = stats_in[lane * SLOTSTR];
    double q = stats_in[lane * SLOTSTR + 1];
    #pragma unroll
    for (int off = 32; off >= 1; off >>= 1) {
        s += __shfl_down(s, off, 64);
        q += __shfl_down(q, off, 64);
    }
    s = __shfl(s, 0, 64);
    q = __shfl(q, 0, 64);
    const double INV_N = 1.0 / (double)NTOT;
    double mean = s * INV_N;
    double var  = q * INV_N - mean * mean;
    float rstd = 1.0f / sqrtf((float)var + 1e-5f);
    float a  = gamma * rstd;
    float bb = beta - (float)mean * a;
    return make_float2(a, bb);
}

// 3x3 conv for 4 horizontally-adjacent pixels. img is the row-padded LDS
// image (LROWS x 28, rows 0/29 zero). Output row r (0..27), cols 4c4..4c4+3.
__device__ __forceinline__ void conv4(const float* img, const float w9[9],
                                      int r, int c4, float o[4]) {
    o[0] = o[1] = o[2] = o[3] = 0.f;
    const int cbase = 4 * c4;
    int li = cbase - 1; li = li < 0 ? 0 : li;      // clamped (value masked below)
    int ri = cbase + 4; ri = ri > 27 ? 27 : ri;
    #pragma unroll
    for (int kr = 0; kr < 3; kr++) {
        const float* row = img + (r + kr) * 28;    // LDS rows r..r+2
        float4 C = *(const float4*)(row + cbase);
        float L = row[li]; L = (c4 == 0) ? 0.f : L;
        float R = row[ri]; R = (c4 == 6) ? 0.f : R;
        float wl = w9[kr * 3], wc = w9[kr * 3 + 1], wr = w9[kr * 3 + 2];
        o[0] = fmaf(wl, L,   fmaf(wc, C.x, fmaf(wr, C.y, o[0])));
        o[1] = fmaf(wl, C.x, fmaf(wc, C.y, fmaf(wr, C.z, o[1])));
        o[2] = fmaf(wl, C.y, fmaf(wc, C.z, fmaf(wr, C.w, o[2])));
        o[3] = fmaf(wl, C.z, fmaf(wc, C.w, fmaf(wr, R,   o[3])));
    }
}

__device__ __forceinline__ void zero_pad_rows(float* img, int t) {
    // threads 196..209 zero rows 0 and 29 (7 float4 each)
    if (t >= 196 && t < 210) {
        int i = t - 196;
        ((float4*)img)[i < 7 ? i : 196 + i] = make_float4(0.f, 0.f, 0.f, 0.f);
    }
}

__device__ __forceinline__ void conv_tail(const float* img, const float w9[9],
                                          float* out_row, double* slot, int t) {
    float lsum = 0.f, lsq = 0.f;
    if (t < 196) {
        int r = t / 7, c4 = t - r * 7;
        float o[4];
        conv4(img, w9, r, c4, o);
        ((float4*)out_row)[t] = make_float4(o[0], o[1], o[2], o[3]);
        lsum = o[0] + o[1] + o[2] + o[3];
        lsq  = fmaf(o[0], o[0], fmaf(o[1], o[1], fmaf(o[2], o[2], o[3] * o[3])));
    }
    block_reduce_stats(lsum, lsq, slot);
}

// Pass 1: y1 = conv(x, w); stats(y1)
__global__ __launch_bounds__(256) void k_conv_plain(const float* __restrict__ in,
        const float* __restrict__ w, float* __restrict__ out, double* __restrict__ stats_out)
{
    __shared__ __align__(16) float img[LROWS * 28];
    const int b = blockIdx.x;
    const int t = threadIdx.x;
    float w9[9];
    #pragma unroll
    for (int i = 0; i < 9; i++) w9[i] = w[i];
    if (t < 196) ((float4*)(img + 28))[t] = ((const float4*)(in + (size_t)b * IMGPIX))[t];
    zero_pad_rows(img, t);
    __syncthreads();
    conv_tail(img, w9, out + (size_t)b * IMGPIX, &stats_out[(b & (NSLOT - 1)) * SLOTSTR], t);
}

// Pass 2/4: h = relu(bn(in)); y = conv(h, w); stats(y)
__global__ __launch_bounds__(256) void k_conv_affine(const float* __restrict__ in,
        const double* __restrict__ stats_in,
        const float* __restrict__ gamma, const float* __restrict__ beta,
        const float* __restrict__ w, float* __restrict__ out, double* __restrict__ stats_out)
{
    __shared__ __align__(16) float img[LROWS * 28];
    const int b = blockIdx.x;
    const int t = threadIdx.x;
    float2 ab = stats_ab(stats_in, gamma[0], beta[0]);
    float w9[9];
    #pragma unroll
    for (int i = 0; i < 9; i++) w9[i] = w[i];
    if (t < 196) {
        float4 v = ((const float4*)(in + (size_t)b * IMGPIX))[t];
        v.x = fmaxf(fmaf(ab.x, v.x, ab.y), 0.f);
        v.y = fmaxf(fmaf(ab.x, v.y, ab.y), 0.f);
        v.z = fmaxf(fmaf(ab.x, v.z, ab.y), 0.f);
        v.w = fmaxf(fmaf(ab.x, v.w, ab.y), 0.f);
        ((float4*)(img + 28))[t] = v;
    }
    zero_pad_rows(img, t);
    __syncthreads();
    conv_tail(img, w9, out + (size_t)b * IMGPIX, &stats_out[(b & (NSLOT - 1)) * SLOTSTR], t);
}

// Pass 3: o1 = relu(bn(y2) + x) [stored]; y3 = conv(o1, w); stats(y3)
__global__ __launch_bounds__(256) void k_conv_resid(const float* __restrict__ y2,
        const float* __restrict__ x, const double* __restrict__ stats_in,
        const float* __restrict__ gamma, const float* __restrict__ beta,
        const float* __restrict__ w, float* __restrict__ y3_out,
        float* __restrict__ o1_out, double* __restrict__ stats_out)
{
    __shared__ __align__(16) float img[LROWS * 28];
    const int b = blockIdx.x;
    const int t = threadIdx.x;
    float2 ab = stats_ab(stats_in, gamma[0], beta[0]);
    float w9[9];
    #pragma unroll
    for (int i = 0; i < 9; i++) w9[i] = w[i];
    if (t < 196) {
        float4 v  = ((const float4*)(y2 + (size_t)b * IMGPIX))[t];
        float4 xv = ((const float4*)(x  + (size_t)b * IMGPIX))[t];
        v.x = fmaxf(fmaf(ab.x, v.x, ab.y) + xv.x, 0.f);
        v.y = fmaxf(fmaf(ab.x, v.y, ab.y) + xv.y, 0.f);
        v.z = fmaxf(fmaf(ab.x, v.z, ab.y) + xv.z, 0.f);
        v.w = fmaxf(fmaf(ab.x, v.w, ab.y) + xv.w, 0.f);
        ((float4*)(img + 28))[t] = v;
        ((float4*)(o1_out + (size_t)b * IMGPIX))[t] = v;
    }
    zero_pad_rows(img, t);
    __syncthreads();
    conv_tail(img, w9, y3_out + (size_t)b * IMGPIX, &stats_out[(b & (NSLOT - 1)) * SLOTSTR], t);
}

// Pass 5: o2 = relu(bn(y4)+o1); logits = alpha*(o2@fcW^T)+qk; log_softmax
#define FC_LD 11
__global__ __launch_bounds__(256) void k_head(const float* __restrict__ y4,
        const float* __restrict__ o1, const double* __restrict__ stats_in,
        const float* __restrict__ gamma, const float* __restrict__ beta,
        const float* __restrict__ fc_w, const float* __restrict__ qk,
        const float* __restrict__ alpha_p, float* __restrict__ out)
{
    __shared__ float fcT[IMGPIX * FC_LD];
    const int t = threadIdx.x;
    float2 ab = stats_ab(stats_in, gamma[0], beta[0]);
    for (int i = t; i < 7840; i += 256) {
        int k = i / 784;
        int j = i - k * 784;
        fcT[j * FC_LD + k] = fc_w[i];
    }
    float alpha = alpha_p[0];
    float qkr[10];
    #pragma unroll
    for (int k = 0; k < 10; k++) qkr[k] = qk[k];
    __syncthreads();

    const int wid  = t >> 6;
    const int lane = t & 63;
    const int row  = blockIdx.x * 4 + wid;   // grid=4096 -> rows 0..16383
    const float* yr   = y4 + (size_t)row * IMGPIX;
    const float* orow = o1 + (size_t)row * IMGPIX;

    float acc[10];
    #pragma unroll
    for (int k = 0; k < 10; k++) acc[k] = 0.f;
    for (int j = lane; j < IMGPIX; j += 64) {
        float v = fmaxf(fmaf(ab.x, yr[j], ab.y) + orow[j], 0.f);
        const float* fr = &fcT[j * FC_LD];
        #pragma unroll
        for (int k = 0; k < 10; k++) acc[k] = fmaf(v, fr[k], acc[k]);
    }
    #pragma unroll
    for (int k = 0; k < 10; k++) {
        #pragma unroll
        for (int off = 1; off < 64; off <<= 1)
            acc[k] += __shfl_xor(acc[k], off, 64);
    }
    float logit[10];
    float m = -1e30f;
    #pragma unroll
    for (int k = 0; k < 10; k++) {
        logit[k] = fmaf(alpha, acc[k], qkr[k]);
        m = fmaxf(m, logit[k]);
    }
    float se = 0.f;
    #pragma unroll
    for (int k = 0; k < 10; k++) se += __expf(logit[k] - m);
    float lse = m + __logf(se);
    if (lane < 10) out[(size_t)row * 10 + lane] = logit[lane] - lse;
}

// Init: zero stats, compute qk[10] = (1-alpha)*c2*sum_{j%4==0} fcw[k,j] + fcb[k]
__global__ __launch_bounds__(256) void k_init(const float* __restrict__ theta,
        const float* __restrict__ fc_w, const float* __restrict__ fc_b,
        const float* __restrict__ alpha_p, float* __restrict__ qk, double* __restrict__ stats)
{
    const int t = threadIdx.x;
    for (int i = t; i < 4 * STAGE_DBL; i += 256) stats[i] = 0.0;
    if (t < 10) {
        float c = 1.f;
        #pragma unroll
        for (int i = 0; i < 24; i++) c *= cosf(theta[i] * 0.5f);
        float c2 = c * c;
        float s = 0.f;
        for (int j = 0; j < 784; j += 4) s += fc_w[t * 784 + j];
        qk[t] = (1.f - alpha_p[0]) * c2 * s + fc_b[t];
    }
}

extern "C" void kernel_launch(void* const* d_in, const int* in_sizes, int n_in,
                              void* d_out, int out_size, void* d_ws, size_t ws_size,
                              hipStream_t stream) {
    const float* x     = (const float*)d_in[0];
    const float* theta = (const float*)d_in[1];
    const float* r1_w1 = (const float*)d_in[2];
    const float* r1_g1 = (const float*)d_in[3];
    const float* r1_b1 = (const float*)d_in[4];
    const float* r1_w2 = (const float*)d_in[5];
    const float* r1_g2 = (const float*)d_in[6];
    const float* r1_b2 = (const float*)d_in[7];
    const float* r2_w1 = (const float*)d_in[8];
    const float* r2_g1 = (const float*)d_in[9];
    const float* r2_b1 = (const float*)d_in[10];
    const float* r2_w2 = (const float*)d_in[11];
    const float* r2_g2 = (const float*)d_in[12];
    const float* r2_b2 = (const float*)d_in[13];
    const float* fc_w  = (const float*)d_in[14];
    const float* fc_b  = (const float*)d_in[15];
    const float* alpha = (const float*)d_in[16];
    float* out = (float*)d_out;

    double* stats = (double*)d_ws;                       // 4 stages * 512 dbl = 16KB
    float*  qk    = (float*)((char*)d_ws + 16384);       // 10 floats
    float*  bufA  = (float*)((char*)d_ws + 32768);       // y1 then y3
    float*  bufB  = bufA + (size_t)NTOT;                 // y2 then y4
    float*  bufD  = bufB + (size_t)NTOT;                 // o1

    double* s_y1 = stats + 0 * STAGE_DBL;
    double* s_y2 = stats + 1 * STAGE_DBL;
    double* s_y3 = stats + 2 * STAGE_DBL;
    double* s_y4 = stats + 3 * STAGE_DBL;

    k_init<<<1, 256, 0, stream>>>(theta, fc_w, fc_b, alpha, qk, stats);
    k_conv_plain<<<BATCH, 256, 0, stream>>>(x, r1_w1, bufA, s_y1);
    k_conv_affine<<<BATCH, 256, 0, stream>>>(bufA, s_y1, r1_g1, r1_b1, r1_w2, bufB, s_y2);
    k_conv_resid<<<BATCH, 256, 0, stream>>>(bufB, x, s_y2, r1_g2, r1_b2, r2_w1, bufA, bufD, s_y3);
    k_conv_affine<<<BATCH, 256, 0, stream>>>(bufA, s_y3, r2_g1, r2_b1, r2_w2, bufB, s_y4);
    k_head<<<4096, 256, 0, stream>>>(bufB, bufD, s_y4, r2_g2, r2_b2, fc_w, qk, alpha, out);
}

// Round 5
// 139.846 us; speedup vs baseline: 1.6196x; 1.6196x over previous
//
#include <hip/hip_runtime.h>
#include <math.h>

#define BATCH   16384
#define IMGPIX  784           // 28*28
#define NTOT    (BATCH * IMGPIX)
#define NSLOT   64            // atomic spread slots per stage
#define SLOTSTR 8             // doubles per slot (64B stride); [0]=sum [1]=sumsq
#define STAGE_DBL (NSLOT * SLOTSTR)

// ---------------- stats helpers ----------------
__device__ __forceinline__ void wave_stats_atomic(float lsum, float lsq, double* slot) {
    #pragma unroll
    for (int off = 32; off >= 1; off >>= 1) {
        lsum += __shfl_down(lsum, off, 64);
        lsq  += __shfl_down(lsq,  off, 64);
    }
    if ((threadIdx.x & 63) == 0) {
        atomicAdd(&slot[0], (double)lsum);
        atomicAdd(&slot[1], (double)lsq);
    }
}

// Per-wave: reduce the 64 stat slots (2 doubles per lane), broadcast; returns
// (a,b) with bn(x) = a*x + b. No barrier needed.
__device__ __forceinline__ float2 stats_ab(const double* __restrict__ stats_in,
                                           float gamma, float beta) {
    int lane = threadIdx.x & 63;
    double s = stats_in[lane * SLOTSTR];
    double q = stats_in[lane * SLOTSTR + 1];
    #pragma unroll
    for (int off = 32; off >= 1; off >>= 1) {
        s += __shfl_down(s, off, 64);
        q += __shfl_down(q, off, 64);
    }
    s = __shfl(s, 0, 64);
    q = __shfl(q, 0, 64);
    const double INV_N = 1.0 / (double)NTOT;
    double mean = s * INV_N;
    double var  = q * INV_N - mean * mean;
    float rstd = 1.0f / sqrtf((float)var + 1e-5f);
    float a  = gamma * rstd;
    float bb = beta - (float)mean * a;
    return make_float2(a, bb);
}

// ---------------- row-streaming conv core ----------------
// Lane layout: lane = i*8 + c4 (i = image-in-wave 0..7, c4 = 0..6 column
// quad, c4==7 idle). Each lane owns cols 4c4..4c4+3 of its image; horizontal
// halo via shfl, vertical via rolling accumulators.

__device__ __forceinline__ float4 hrow(float wl, float wc, float wr,
                                       float L, float4 v, float R) {
    float4 h;
    h.x = fmaf(wl, L,   fmaf(wc, v.x, wr * v.y));
    h.y = fmaf(wl, v.x, fmaf(wc, v.y, wr * v.z));
    h.z = fmaf(wl, v.y, fmaf(wc, v.z, wr * v.w));
    h.w = fmaf(wl, v.z, fmaf(wc, v.w, wr * R));
    return h;
}

__device__ __forceinline__ void emit_row(float* dst, int r, float4 o, float mf,
                                         float& lsum, float& lsq, bool act) {
    if (act) *(float4*)(dst + r * 28) = o;
    float s4 = (o.x + o.y) + (o.z + o.w);
    float q4 = fmaf(o.x, o.x, fmaf(o.y, o.y, fmaf(o.z, o.z, o.w * o.w)));
    lsum = fmaf(mf, s4, lsum);
    lsq  = fmaf(mf, q4, lsq);
}

#define LANE_SETUP()                                                          \
    const int t = threadIdx.x;                                                \
    const int lane = t & 63;                                                  \
    const int widx = t >> 6;                                                  \
    const int c4   = lane & 7;                                                \
    const bool act = (c4 < 7);                                                \
    const float mf = act ? 1.f : 0.f;                                         \
    const int c4c  = c4 < 7 ? c4 : 6;  /* clamp idle lane addresses */        \
    const int img  = blockIdx.x * 32 + widx * 8 + (lane >> 3);                \
    const size_t ibase = (size_t)img * IMGPIX + c4c * 4;

#define CONV_STEP(v)                                                          \
    {                                                                         \
        float L = __shfl_up((v).w, 1, 64);  if (c4 == 0) L = 0.f;             \
        float R = __shfl_down((v).x, 1, 64); if (c4 == 6) R = 0.f;            \
        float4 h2 = hrow(w9[6], w9[7], w9[8], L, (v), R);                     \
        float4 h1 = hrow(w9[3], w9[4], w9[5], L, (v), R);                     \
        float4 h0 = hrow(w9[0], w9[1], w9[2], L, (v), R);                     \
        if (rr == 0) { accA = h1; accB = h0; }                                \
        else {                                                                \
            accA.x += h2.x; accA.y += h2.y; accA.z += h2.z; accA.w += h2.w;   \
            emit_row(dst, rr - 1, accA, mf, lsum, lsq, act);                  \
            accA.x = accB.x + h1.x; accA.y = accB.y + h1.y;                   \
            accA.z = accB.z + h1.z; accA.w = accB.w + h1.w;                   \
            accB = h0;                                                        \
        }                                                                     \
    }

// Pass 1: y1 = conv(x, w); stats(y1)
__global__ __launch_bounds__(256) void k_conv_plain(const float* __restrict__ in,
        const float* __restrict__ w, float* __restrict__ out, double* __restrict__ stats_out)
{
    LANE_SETUP();
    float w9[9];
    #pragma unroll
    for (int i = 0; i < 9; i++) w9[i] = w[i];
    const float* src = in + ibase;
    float* dst = out + ibase - c4c * 4 + c4 * 4;   // act lanes: true base
    dst = out + (size_t)img * IMGPIX + c4 * 4;     // (idle lanes never store)

    const int D = 8;
    float4 buf[D];
    #pragma unroll
    for (int k = 0; k < D; k++) buf[k] = *(const float4*)(src + k * 28);

    float4 accA, accB;
    float lsum = 0.f, lsq = 0.f;
    #pragma unroll
    for (int rr = 0; rr < 28; rr++) {
        float4 v = buf[rr % D];
        if (rr + D < 28) buf[rr % D] = *(const float4*)(src + (rr + D) * 28);
        CONV_STEP(v);
    }
    emit_row(dst, 27, accA, mf, lsum, lsq, act);
    wave_stats_atomic(lsum, lsq, &stats_out[((blockIdx.x * 4 + widx) & (NSLOT - 1)) * SLOTSTR]);
}

// Pass 2/4: h = relu(bn(in)); y = conv(h, w); stats(y)
__global__ __launch_bounds__(256) void k_conv_affine(const float* __restrict__ in,
        const double* __restrict__ stats_in,
        const float* __restrict__ gamma, const float* __restrict__ beta,
        const float* __restrict__ w, float* __restrict__ out, double* __restrict__ stats_out)
{
    LANE_SETUP();
    float2 ab = stats_ab(stats_in, gamma[0], beta[0]);
    float w9[9];
    #pragma unroll
    for (int i = 0; i < 9; i++) w9[i] = w[i];
    const float* src = in + ibase;
    float* dst = out + (size_t)img * IMGPIX + c4 * 4;

    const int D = 8;
    float4 buf[D];
    #pragma unroll
    for (int k = 0; k < D; k++) buf[k] = *(const float4*)(src + k * 28);

    float4 accA, accB;
    float lsum = 0.f, lsq = 0.f;
    #pragma unroll
    for (int rr = 0; rr < 28; rr++) {
        float4 r4 = buf[rr % D];
        if (rr + D < 28) buf[rr % D] = *(const float4*)(src + (rr + D) * 28);
        float4 v;
        v.x = fmaxf(fmaf(ab.x, r4.x, ab.y), 0.f);
        v.y = fmaxf(fmaf(ab.x, r4.y, ab.y), 0.f);
        v.z = fmaxf(fmaf(ab.x, r4.z, ab.y), 0.f);
        v.w = fmaxf(fmaf(ab.x, r4.w, ab.y), 0.f);
        CONV_STEP(v);
    }
    emit_row(dst, 27, accA, mf, lsum, lsq, act);
    wave_stats_atomic(lsum, lsq, &stats_out[((blockIdx.x * 4 + widx) & (NSLOT - 1)) * SLOTSTR]);
}

// Pass 3: o1 = relu(bn(y2) + x) [stored]; y3 = conv(o1, w); stats(y3)
__global__ __launch_bounds__(256) void k_conv_resid(const float* __restrict__ y2,
        const float* __restrict__ x, const double* __restrict__ stats_in,
        const float* __restrict__ gamma, const float* __restrict__ beta,
        const float* __restrict__ w, float* __restrict__ y3_out,
        float* __restrict__ o1_out, double* __restrict__ stats_out)
{
    LANE_SETUP();
    float2 ab = stats_ab(stats_in, gamma[0], beta[0]);
    float w9[9];
    #pragma unroll
    for (int i = 0; i < 9; i++) w9[i] = w[i];
    const float* srcy = y2 + ibase;
    const float* srcx = x + ibase;
    float* dst  = y3_out + (size_t)img * IMGPIX + c4 * 4;
    float* dsto = o1_out + (size_t)img * IMGPIX + c4 * 4;

    const int D = 6;
    float4 yb[D], xb[D];
    #pragma unroll
    for (int k = 0; k < D; k++) {
        yb[k] = *(const float4*)(srcy + k * 28);
        xb[k] = *(const float4*)(srcx + k * 28);
    }

    float4 accA, accB;
    float lsum = 0.f, lsq = 0.f;
    #pragma unroll
    for (int rr = 0; rr < 28; rr++) {
        float4 r4 = yb[rr % D];
        float4 x4 = xb[rr % D];
        if (rr + D < 28) {
            yb[rr % D] = *(const float4*)(srcy + (rr + D) * 28);
            xb[rr % D] = *(const float4*)(srcx + (rr + D) * 28);
        }
        float4 v;
        v.x = fmaxf(fmaf(ab.x, r4.x, ab.y) + x4.x, 0.f);
        v.y = fmaxf(fmaf(ab.x, r4.y, ab.y) + x4.y, 0.f);
        v.z = fmaxf(fmaf(ab.x, r4.z, ab.y) + x4.z, 0.f);
        v.w = fmaxf(fmaf(ab.x, r4.w, ab.y) + x4.w, 0.f);
        if (act) *(float4*)(dsto + rr * 28) = v;
        CONV_STEP(v);
    }
    emit_row(dst, 27, accA, mf, lsum, lsq, act);
    wave_stats_atomic(lsum, lsq, &stats_out[((blockIdx.x * 4 + widx) & (NSLOT - 1)) * SLOTSTR]);
}

// Pass 5: o2 = relu(bn(y4)+o1); logits = alpha*(o2@fcW^T)+qk; log_softmax
#define FC_LD 11
__global__ __launch_bounds__(256) void k_head(const float* __restrict__ y4,
        const float* __restrict__ o1, const double* __restrict__ stats_in,
        const float* __restrict__ gamma, const float* __restrict__ beta,
        const float* __restrict__ fc_w, const float* __restrict__ qk,
        const float* __restrict__ alpha_p, float* __restrict__ out)
{
    __shared__ float fcT[IMGPIX * FC_LD];
    const int t = threadIdx.x;
    float2 ab = stats_ab(stats_in, gamma[0], beta[0]);
    for (int i = t; i < 7840; i += 256) {
        int k = i / 784;
        int j = i - k * 784;
        fcT[j * FC_LD + k] = fc_w[i];
    }
    float alpha = alpha_p[0];
    float qkr[10];
    #pragma unroll
    for (int k = 0; k < 10; k++) qkr[k] = qk[k];
    __syncthreads();

    const int wid  = t >> 6;
    const int lane = t & 63;
    const int row  = blockIdx.x * 4 + wid;   // grid=4096 -> rows 0..16383
    const float* yr   = y4 + (size_t)row * IMGPIX;
    const float* orow = o1 + (size_t)row * IMGPIX;

    float acc[10];
    #pragma unroll
    for (int k = 0; k < 10; k++) acc[k] = 0.f;
    for (int j = lane; j < IMGPIX; j += 64) {
        float v = fmaxf(fmaf(ab.x, yr[j], ab.y) + orow[j], 0.f);
        const float* fr = &fcT[j * FC_LD];
        #pragma unroll
        for (int k = 0; k < 10; k++) acc[k] = fmaf(v, fr[k], acc[k]);
    }
    #pragma unroll
    for (int k = 0; k < 10; k++) {
        #pragma unroll
        for (int off = 1; off < 64; off <<= 1)
            acc[k] += __shfl_xor(acc[k], off, 64);
    }
    float logit[10];
    float m = -1e30f;
    #pragma unroll
    for (int k = 0; k < 10; k++) {
        logit[k] = fmaf(alpha, acc[k], qkr[k]);
        m = fmaxf(m, logit[k]);
    }
    float se = 0.f;
    #pragma unroll
    for (int k = 0; k < 10; k++) se += __expf(logit[k] - m);
    float lse = m + __logf(se);
    if (lane < 10) out[(size_t)row * 10 + lane] = logit[lane] - lse;
}

// Init: zero stats, compute qk[10] = (1-alpha)*c2*sum_{j%4==0} fcw[k,j] + fcb[k]
__global__ __launch_bounds__(256) void k_init(const float* __restrict__ theta,
        const float* __restrict__ fc_w, const float* __restrict__ fc_b,
        const float* __restrict__ alpha_p, float* __restrict__ qk, double* __restrict__ stats)
{
    const int t = threadIdx.x;
    for (int i = t; i < 4 * STAGE_DBL; i += 256) stats[i] = 0.0;
    if (t < 10) {
        float c = 1.f;
        #pragma unroll
        for (int i = 0; i < 24; i++) c *= cosf(theta[i] * 0.5f);
        float c2 = c * c;
        float s = 0.f;
        for (int j = 0; j < 784; j += 4) s += fc_w[t * 784 + j];
        qk[t] = (1.f - alpha_p[0]) * c2 * s + fc_b[t];
    }
}

extern "C" void kernel_launch(void* const* d_in, const int* in_sizes, int n_in,
                              void* d_out, int out_size, void* d_ws, size_t ws_size,
                              hipStream_t stream) {
    const float* x     = (const float*)d_in[0];
    const float* theta = (const float*)d_in[1];
    const float* r1_w1 = (const float*)d_in[2];
    const float* r1_g1 = (const float*)d_in[3];
    const float* r1_b1 = (const float*)d_in[4];
    const float* r1_w2 = (const float*)d_in[5];
    const float* r1_g2 = (const float*)d_in[6];
    const float* r1_b2 = (const float*)d_in[7];
    const float* r2_w1 = (const float*)d_in[8];
    const float* r2_g1 = (const float*)d_in[9];
    const float* r2_b1 = (const float*)d_in[10];
    const float* r2_w2 = (const float*)d_in[11];
    const float* r2_g2 = (const float*)d_in[12];
    const float* r2_b2 = (const float*)d_in[13];
    const float* fc_w  = (const float*)d_in[14];
    const float* fc_b  = (const float*)d_in[15];
    const float* alpha = (const float*)d_in[16];
    float* out = (float*)d_out;

    double* stats = (double*)d_ws;                       // 4 stages * 512 dbl = 16KB
    float*  qk    = (float*)((char*)d_ws + 16384);       // 10 floats
    float*  bufA  = (float*)((char*)d_ws + 32768);       // y1 then y3
    float*  bufB  = bufA + (size_t)NTOT;                 // y2 then y4
    float*  bufD  = bufB + (size_t)NTOT;                 // o1

    double* s_y1 = stats + 0 * STAGE_DBL;
    double* s_y2 = stats + 1 * STAGE_DBL;
    double* s_y3 = stats + 2 * STAGE_DBL;
    double* s_y4 = stats + 3 * STAGE_DBL;

    k_init<<<1, 256, 0, stream>>>(theta, fc_w, fc_b, alpha, qk, stats);
    k_conv_plain<<<512, 256, 0, stream>>>(x, r1_w1, bufA, s_y1);
    k_conv_affine<<<512, 256, 0, stream>>>(bufA, s_y1, r1_g1, r1_b1, r1_w2, bufB, s_y2);
    k_conv_resid<<<512, 256, 0, stream>>>(bufB, x, s_y2, r1_g2, r1_b2, r2_w1, bufA, bufD, s_y3);
    k_conv_affine<<<512, 256, 0, stream>>>(bufA, s_y3, r2_g1, r2_b1, r2_w2, bufB, s_y4);
    k_head<<<4096, 256, 0, stream>>>(bufB, bufD, s_y4, r2_g2, r2_b2, fc_w, qk, alpha, out);
}